// Round 1
// baseline (566.933 us; speedup 1.0000x reference)
//
#include <hip/hip_runtime.h>

#define NN 20000
#define NE 640000
#define CH 128
#define NG 64

// ---------------- CSR build (dst-sorted adjacency) ----------------
__global__ void count_deg(const int* __restrict__ ei, int* __restrict__ degcnt) {
    int e = blockIdx.x * blockDim.x + threadIdx.x;
    if (e < NE) atomicAdd(&degcnt[ei[NE + e]], 1);
}

// single-block exclusive scan of degcnt[NN] -> off[NN+1]
__global__ void scan_deg(const int* __restrict__ degcnt, int* __restrict__ off) {
    __shared__ int psum[256];
    __shared__ int ex[256];
    int t = threadIdx.x;
    const int chunk = (NN + 255) / 256;  // 79
    int lo = t * chunk;
    int hi = lo + chunk; if (hi > NN) hi = NN; if (lo > NN) lo = NN;
    int s = 0;
    for (int i = lo; i < hi; ++i) s += degcnt[i];
    psum[t] = s;
    __syncthreads();
    if (t == 0) {
        int run = 0;
        for (int i = 0; i < 256; ++i) { ex[i] = run; run += psum[i]; }
    }
    __syncthreads();
    int run = ex[t];
    for (int i = lo; i < hi; ++i) { off[i] = run; run += degcnt[i]; }
    if (t == 0) off[NN] = NE;
}

__global__ void fill_csr(const int* __restrict__ ei, const int* __restrict__ off,
                         int* __restrict__ fillc, int* __restrict__ ssrc) {
    int e = blockIdx.x * blockDim.x + threadIdx.x;
    if (e < NE) {
        int dst = ei[NE + e];
        int pos = off[dst] + atomicAdd(&fillc[dst], 1);
        ssrc[pos] = ei[e];  // src
    }
}

// ---------------- aggregate: out[n] = in[n] + sum_{e:dst==n} in[src[e]] ----------------
__global__ __launch_bounds__(256) void aggregate(const float* __restrict__ in,
                                                 float* __restrict__ out,
                                                 const int* __restrict__ off,
                                                 const int* __restrict__ ssrc) {
    int n = blockIdx.x * 2 + (threadIdx.x >> 7);   // 2 nodes / block
    int c = threadIdx.x & 127;
    float acc = in[n * CH + c];
    int b = off[n], e = off[n + 1];
    for (int i = b; i < e; ++i) {
        int s = ssrc[i];                  // wave-uniform -> broadcast
        acc += in[s * CH + c];            // coalesced 512B row gather
    }
    out[n * CH + c] = acc;
}

// ---------------- GEMM: out = relu?(A @ W + bias), A[NN][128], W[128][128] ----------------
// tile: 64 rows x 128 cols, K-tiles of 64. 128 threads: tx=t&15 (cols), ty=t>>4 (rows).
// thread owns rows {ty*4+i, 32+ty*4+i} and cols {tx*4+j, 64+tx*4+j}  -> acc[8][8]
__global__ __launch_bounds__(128) void gemm_bias(const float* __restrict__ A,
                                                 const float* __restrict__ W,
                                                 const float* __restrict__ bias,
                                                 float* __restrict__ out, int relu) {
    __shared__ __align__(16) float As[64 * 68];   // As[k][row], stride 68 (16B-aligned rows)
    __shared__ __align__(16) float Ws[64 * 128];  // Ws[k][col]
    int t = threadIdx.x;
    int row0 = blockIdx.x * 64;
    int tx = t & 15, ty = t >> 4;

    float acc[8][8];
    #pragma unroll
    for (int i = 0; i < 8; ++i)
        #pragma unroll
        for (int j = 0; j < 8; ++j) acc[i][j] = 0.f;

    for (int kt = 0; kt < 2; ++kt) {
        int k0 = kt * 64;
        // A chunk: 64 rows x 64 k = 4096 floats, 8 float4/thread, store transposed
        #pragma unroll
        for (int i = 0; i < 8; ++i) {
            int f = (t + i * 128) * 4;       // 0..4095
            int r = f >> 6, k = f & 63;
            int gr = row0 + r; if (gr >= NN) gr = NN - 1;
            float4 v = *(const float4*)(A + (size_t)gr * CH + k0 + k);
            As[(k + 0) * 68 + r] = v.x;
            As[(k + 1) * 68 + r] = v.y;
            As[(k + 2) * 68 + r] = v.z;
            As[(k + 3) * 68 + r] = v.w;
        }
        // W chunk: 64 k x 128 cols = 8192 floats, 16 float4/thread
        #pragma unroll
        for (int i = 0; i < 16; ++i) {
            int f = (t + i * 128) * 4;       // 0..8191
            int k = f >> 7, c = f & 127;
            *(float4*)&Ws[f] = *(const float4*)(W + (size_t)(k0 + k) * CH + c);
        }
        __syncthreads();
        #pragma unroll 8
        for (int k = 0; k < 64; ++k) {
            float4 a0 = *(const float4*)&As[k * 68 + ty * 4];
            float4 a1 = *(const float4*)&As[k * 68 + 32 + ty * 4];
            float4 w0 = *(const float4*)&Ws[k * 128 + tx * 4];
            float4 w1 = *(const float4*)&Ws[k * 128 + 64 + tx * 4];
            float av[8] = {a0.x, a0.y, a0.z, a0.w, a1.x, a1.y, a1.z, a1.w};
            float wv[8] = {w0.x, w0.y, w0.z, w0.w, w1.x, w1.y, w1.z, w1.w};
            #pragma unroll
            for (int i = 0; i < 8; ++i)
                #pragma unroll
                for (int j = 0; j < 8; ++j)
                    acc[i][j] += av[i] * wv[j];
        }
        __syncthreads();
    }

    float4 bw0 = *(const float4*)(bias + tx * 4);
    float4 bw1 = *(const float4*)(bias + 64 + tx * 4);
    float bv[8] = {bw0.x, bw0.y, bw0.z, bw0.w, bw1.x, bw1.y, bw1.z, bw1.w};
    #pragma unroll
    for (int iq = 0; iq < 2; ++iq) {
        #pragma unroll
        for (int i = 0; i < 4; ++i) {
            int r = row0 + iq * 32 + ty * 4 + i;
            if (r < NN) {
                float o[8];
                #pragma unroll
                for (int j = 0; j < 8; ++j) {
                    float v = acc[iq * 4 + i][j] + bv[j];
                    o[j] = relu ? fmaxf(v, 0.f) : v;
                }
                *(float4*)(out + (size_t)r * CH + tx * 4)      = make_float4(o[0], o[1], o[2], o[3]);
                *(float4*)(out + (size_t)r * CH + 64 + tx * 4) = make_float4(o[4], o[5], o[6], o[7]);
            }
        }
    }
}

// ---------------- fused mean-pool + fc (batch is sorted) ----------------
__global__ __launch_bounds__(256) void pool_fc(const float* __restrict__ h,
                                               const int* __restrict__ batch,
                                               const float* __restrict__ fcw,
                                               const float* __restrict__ fcb,
                                               float* __restrict__ out) {
    int g = blockIdx.x;
    int t = threadIdx.x;
    __shared__ int sse[2];
    if (t < 2) {
        int target = g + t;   // first idx with batch[i] >= target
        int lo = 0, hi = NN;
        while (lo < hi) { int mid = (lo + hi) >> 1; if (batch[mid] < target) lo = mid + 1; else hi = mid; }
        sse[t] = lo;
    }
    __syncthreads();
    int start = sse[0], end = sse[1];
    int c = t & 127, half = t >> 7;
    float acc = 0.f;
    for (int n = start + half; n < end; n += 2)
        acc += h[(size_t)n * CH + c];
    __shared__ float red[256];
    red[t] = acc * fcw[c];
    __syncthreads();
    for (int s = 128; s > 0; s >>= 1) {
        if (t < s) red[t] += red[t + s];
        __syncthreads();
    }
    if (t == 0) {
        int cnt = end - start; if (cnt < 1) cnt = 1;
        out[g] = red[0] / (float)cnt + fcb[0];
    }
}

extern "C" void kernel_launch(void* const* d_in, const int* in_sizes, int n_in,
                              void* d_out, int out_size, void* d_ws, size_t ws_size,
                              hipStream_t stream) {
    const float* x   = (const float*)d_in[0];
    const int*   ei  = (const int*)d_in[1];    // [2][NE]: row0=src, row1=dst
    const int* batch = (const int*)d_in[2];
    const float* W1a = (const float*)d_in[3];
    const float* b1a = (const float*)d_in[4];
    const float* W1b = (const float*)d_in[5];
    const float* b1b = (const float*)d_in[6];
    const float* W2a = (const float*)d_in[7];
    const float* b2a = (const float*)d_in[8];
    const float* W2b = (const float*)d_in[9];
    const float* b2b = (const float*)d_in[10];
    const float* fcw = (const float*)d_in[11];
    const float* fcb = (const float*)d_in[12];
    float* out = (float*)d_out;

    char* w = (char*)d_ws;
    float* bufA = (float*)w;  w += (size_t)NN * CH * 4;
    float* bufB = (float*)w;  w += (size_t)NN * CH * 4;
    int* off    = (int*)w;    w += (size_t)(NN + 1) * 4;
    int* degcnt = (int*)w;    w += (size_t)NN * 4;
    int* fillc  = (int*)w;    w += (size_t)NN * 4;
    int* ssrc   = (int*)w;    w += (size_t)NE * 4;

    // zero off+degcnt+fillc (contiguous)
    hipMemsetAsync(off, 0, (size_t)(NN + 1 + NN + NN) * 4, stream);
    count_deg<<<(NE + 255) / 256, 256, 0, stream>>>(ei, degcnt);
    scan_deg<<<1, 256, 0, stream>>>(degcnt, off);
    fill_csr<<<(NE + 255) / 256, 256, 0, stream>>>(ei, off, fillc, ssrc);

    // layer 1
    aggregate<<<NN / 2, 256, 0, stream>>>(x, bufA, off, ssrc);
    gemm_bias<<<(NN + 63) / 64, 128, 0, stream>>>(bufA, W1a, b1a, bufB, 1);
    gemm_bias<<<(NN + 63) / 64, 128, 0, stream>>>(bufB, W1b, b1b, bufA, 1); // fused outer relu
    // layer 2
    aggregate<<<NN / 2, 256, 0, stream>>>(bufA, bufB, off, ssrc);
    gemm_bias<<<(NN + 63) / 64, 128, 0, stream>>>(bufB, W2a, b2a, bufA, 1);
    gemm_bias<<<(NN + 63) / 64, 128, 0, stream>>>(bufA, W2b, b2b, bufB, 1); // fused outer relu
    // pool + fc
    pool_fc<<<NG, 256, 0, stream>>>(bufB, batch, fcw, fcb, out);
}

// Round 2
// 317.667 us; speedup vs baseline: 1.7847x; 1.7847x over previous
//
#include <hip/hip_runtime.h>

#define NN 20000
#define NE 640000
#define CH 128
#define NG 64

typedef unsigned short u16;
typedef __attribute__((ext_vector_type(8))) short short8;   // 8 bf16 (4 VGPRs)
typedef __attribute__((ext_vector_type(4))) float floatx4;  // 4 fp32 acc

__device__ __forceinline__ float b2f(u16 u) {
    union { float f; unsigned int i; } v; v.i = ((unsigned int)u) << 16; return v.f;
}
__device__ __forceinline__ u16 f2b(float f) {
    unsigned int u = __float_as_uint(f);
    u += 0x7fff + ((u >> 16) & 1);          // RNE
    return (u16)(u >> 16);
}

// ---------------- convert x -> bf16, weights -> bf16 transposed (Wt[n][k] = W[k][n]) --------
__global__ __launch_bounds__(256) void cvt_all(const float* __restrict__ x, u16* __restrict__ xb,
                                               const float* __restrict__ W1a, const float* __restrict__ W1b,
                                               const float* __restrict__ W2a, const float* __restrict__ W2b,
                                               u16* __restrict__ wt) {
    int b = blockIdx.x;
    if (b < 2500) {                                   // x: 2.56M elems, 4/thread
        int idx = (b * 256 + threadIdx.x) * 4;
        float4 v = *(const float4*)(x + idx);
        u16 o0 = f2b(v.x), o1 = f2b(v.y), o2 = f2b(v.z), o3 = f2b(v.w);
        ushort4 o = make_ushort4(o0, o1, o2, o3);
        *(ushort4*)(xb + idx) = o;
    } else {                                          // weights: 4 x 16384, 1/thread
        int wi = b - 2500;                            // 0..255
        int m = wi >> 6;
        int r = (wi & 63) * 256 + threadIdx.x;        // output elem in matrix
        int n = r >> 7, k = r & 127;
        const float* W = (m == 0) ? W1a : (m == 1) ? W1b : (m == 2) ? W2a : W2b;
        wt[m * 16384 + n * 128 + k] = f2b(W[k * 128 + n]);
    }
}

// ---------------- CSR build (dst-sorted adjacency) ----------------
__global__ void count_deg(const int* __restrict__ ei, int* __restrict__ degcnt) {
    int e = blockIdx.x * blockDim.x + threadIdx.x;
    if (e < NE) atomicAdd(&degcnt[ei[NE + e]], 1);
}

__global__ void scan_deg(const int* __restrict__ degcnt, int* __restrict__ off) {
    __shared__ int psum[256];
    __shared__ int ex[256];
    int t = threadIdx.x;
    const int chunk = (NN + 255) / 256;
    int lo = t * chunk;
    int hi = lo + chunk; if (hi > NN) hi = NN; if (lo > NN) lo = NN;
    int s = 0;
    for (int i = lo; i < hi; ++i) s += degcnt[i];
    psum[t] = s;
    __syncthreads();
    if (t == 0) {
        int run = 0;
        for (int i = 0; i < 256; ++i) { ex[i] = run; run += psum[i]; }
    }
    __syncthreads();
    int run = ex[t];
    for (int i = lo; i < hi; ++i) { off[i] = run; run += degcnt[i]; }
    if (t == 0) off[NN] = NE;
}

__global__ void fill_csr(const int* __restrict__ ei, const int* __restrict__ off,
                         int* __restrict__ fillc, int* __restrict__ ssrc) {
    int e = blockIdx.x * blockDim.x + threadIdx.x;
    if (e < NE) {
        int dst = ei[NE + e];
        int pos = off[dst] + atomicAdd(&fillc[dst], 1);
        ssrc[pos] = ei[e];
    }
}

// ---------------- aggregate (bf16): out[n] = in[n] + sum_{e:dst==n} in[src[e]] ----------------
// one wave per node: 4 edge-slots x 16 ch-groups (8 ch each, 16B loads); 2x unroll -> 8 loads in flight
__global__ __launch_bounds__(256) void agg_bf16(const u16* __restrict__ in, u16* __restrict__ out,
                                                const int* __restrict__ off, const int* __restrict__ ssrc) {
    int n = (blockIdx.x * 256 + threadIdx.x) >> 6;
    int lane = threadIdx.x & 63;
    int slot = lane >> 4, cg = lane & 15;
    int boff = cg * 8;
    float acc[8];
    if (slot == 0) {
        short8 v = *(const short8*)(in + (size_t)n * CH + boff);
        #pragma unroll
        for (int j = 0; j < 8; ++j) acc[j] = b2f((u16)v[j]);
    } else {
        #pragma unroll
        for (int j = 0; j < 8; ++j) acc[j] = 0.f;
    }
    int b = off[n], e = off[n + 1];
    int i = b + slot;
    for (; i + 4 < e; i += 8) {
        int s0 = ssrc[i], s1 = ssrc[i + 4];
        short8 v0 = *(const short8*)(in + (size_t)s0 * CH + boff);
        short8 v1 = *(const short8*)(in + (size_t)s1 * CH + boff);
        #pragma unroll
        for (int j = 0; j < 8; ++j) acc[j] += b2f((u16)v0[j]) + b2f((u16)v1[j]);
    }
    for (; i < e; i += 4) {
        int s0 = ssrc[i];
        short8 v0 = *(const short8*)(in + (size_t)s0 * CH + boff);
        #pragma unroll
        for (int j = 0; j < 8; ++j) acc[j] += b2f((u16)v0[j]);
    }
    #pragma unroll
    for (int j = 0; j < 8; ++j) {
        acc[j] += __shfl_xor(acc[j], 16);
        acc[j] += __shfl_xor(acc[j], 32);
    }
    if (slot == 0) {
        short8 o;
        #pragma unroll
        for (int j = 0; j < 8; ++j) o[j] = (short)f2b(acc[j]);
        *(short8*)(out + (size_t)n * CH + boff) = o;
    }
}

// ---------------- MFMA GEMM: out = relu(A @ W + bias), A[NN][128] bf16, Wt[n][k] bf16 -------
// block: 256 thr = 4 waves, 128 rows/block; wave: 32 rows x 128 cols, 64 mfma_16x16x32
__global__ __launch_bounds__(256) void gemm_mfma(const u16* __restrict__ A, const u16* __restrict__ Wt,
                                                 const float* __restrict__ bias, u16* __restrict__ out,
                                                 int relu) {
    __shared__ u16 Ws[128 * 136];                      // [n][k], +8 pad -> 2-way banks (free)
    int t = threadIdx.x;
    #pragma unroll
    for (int i = 0; i < 8; ++i) {                      // stage 32KB of Wt
        int ch = t + i * 256;
        int row = ch >> 4, koff = (ch & 15) * 8;
        *(short8*)&Ws[row * 136 + koff] = *(const short8*)(Wt + ch * 8);
    }
    int wave = t >> 6, lane = t & 63;
    int quad = lane >> 4, l16 = lane & 15;
    int row0 = blockIdx.x * 128 + wave * 32;

    short8 af[2][4];                                   // A-frags: A[m=l16][k=quad*8+j]
    #pragma unroll
    for (int rt = 0; rt < 2; ++rt) {
        int r = row0 + rt * 16 + l16; if (r >= NN) r = NN - 1;
        #pragma unroll
        for (int kc = 0; kc < 4; ++kc)
            af[rt][kc] = *(const short8*)(A + (size_t)r * CH + kc * 32 + quad * 8);
    }
    __syncthreads();

    floatx4 acc[2][8];
    #pragma unroll
    for (int rt = 0; rt < 2; ++rt)
        #pragma unroll
        for (int ct = 0; ct < 8; ++ct) acc[rt][ct] = (floatx4)(0.f);

    #pragma unroll
    for (int ct = 0; ct < 8; ++ct) {
        #pragma unroll
        for (int kc = 0; kc < 4; ++kc) {
            short8 bf = *(const short8*)&Ws[(ct * 16 + l16) * 136 + kc * 32 + quad * 8];
            acc[0][ct] = __builtin_amdgcn_mfma_f32_16x16x32_bf16(af[0][kc], bf, acc[0][ct], 0, 0, 0);
            acc[1][ct] = __builtin_amdgcn_mfma_f32_16x16x32_bf16(af[1][kc], bf, acc[1][ct], 0, 0, 0);
        }
    }
    #pragma unroll
    for (int ct = 0; ct < 8; ++ct) {
        int col = ct * 16 + l16;
        float bv = bias[col];
        #pragma unroll
        for (int rt = 0; rt < 2; ++rt) {
            #pragma unroll
            for (int r = 0; r < 4; ++r) {
                int row = row0 + rt * 16 + quad * 4 + r;   // C/D: row=quad*4+reg, col=lane&15
                if (row < NN) {
                    float v = acc[rt][ct][r] + bv;
                    if (relu) v = fmaxf(v, 0.f);
                    out[(size_t)row * CH + col] = f2b(v);
                }
            }
        }
    }
}

// ---------------- pool: run-length partial sums -> atomics, then per-graph fc ----------------
__global__ __launch_bounds__(256) void pool_partial(const u16* __restrict__ h, const int* __restrict__ batch,
                                                    float* __restrict__ gsum) {
    int n0 = blockIdx.x * 40;
    int n1 = n0 + 40; if (n1 > NN) n1 = NN;
    int half = threadIdx.x >> 7, c = threadIdx.x & 127;
    float run = 0.f; int curg = -1;
    for (int n = n0 + half; n < n1; n += 2) {
        int g = batch[n];
        if (g != curg) {
            if (curg >= 0) atomicAdd(&gsum[curg * CH + c], run);
            run = 0.f; curg = g;
        }
        run += b2f(h[(size_t)n * CH + c]);
    }
    if (curg >= 0) atomicAdd(&gsum[curg * CH + c], run);
}

__global__ __launch_bounds__(128) void pool_final(const float* __restrict__ gsum, const int* __restrict__ batch,
                                                  const float* __restrict__ fcw, const float* __restrict__ fcb,
                                                  float* __restrict__ outp) {
    int g = blockIdx.x, t = threadIdx.x;
    __shared__ int se[2];
    if (t < 2) {
        int target = g + t, lo = 0, hi = NN;
        while (lo < hi) { int mid = (lo + hi) >> 1; if (batch[mid] < target) lo = mid + 1; else hi = mid; }
        se[t] = lo;
    }
    __syncthreads();
    int cnt = se[1] - se[0]; if (cnt < 1) cnt = 1;
    float v = gsum[g * CH + t] * fcw[t] / (float)cnt;
    __shared__ float red[128];
    red[t] = v; __syncthreads();
    for (int s = 64; s > 0; s >>= 1) { if (t < s) red[t] += red[t + s]; __syncthreads(); }
    if (t == 0) outp[g] = red[0] + fcb[0];
}

extern "C" void kernel_launch(void* const* d_in, const int* in_sizes, int n_in,
                              void* d_out, int out_size, void* d_ws, size_t ws_size,
                              hipStream_t stream) {
    const float* x   = (const float*)d_in[0];
    const int*   ei  = (const int*)d_in[1];
    const int* batch = (const int*)d_in[2];
    const float* W1a = (const float*)d_in[3];
    const float* b1a = (const float*)d_in[4];
    const float* W1b = (const float*)d_in[5];
    const float* b1b = (const float*)d_in[6];
    const float* W2a = (const float*)d_in[7];
    const float* b2a = (const float*)d_in[8];
    const float* W2b = (const float*)d_in[9];
    const float* b2b = (const float*)d_in[10];
    const float* fcw = (const float*)d_in[11];
    const float* fcb = (const float*)d_in[12];
    float* out = (float*)d_out;

    char* w = (char*)d_ws;
    u16* xb   = (u16*)w; w += (size_t)NN * CH * 2;
    u16* bufA = (u16*)w; w += (size_t)NN * CH * 2;
    u16* bufB = (u16*)w; w += (size_t)NN * CH * 2;
    u16* wt   = (u16*)w; w += (size_t)4 * 128 * 128 * 2;
    int* off  = (int*)w; w += (size_t)(NN + 1) * 4;
    int* degcnt = (int*)w; w += (size_t)NN * 4;
    int* fillc  = (int*)w; w += (size_t)NN * 4;
    float* gsum = (float*)w; w += (size_t)NG * CH * 4;
    int* ssrc   = (int*)w; w += (size_t)NE * 4;

    // zero degcnt + fillc + gsum (contiguous)
    hipMemsetAsync(degcnt, 0, (size_t)(NN + NN + NG * CH) * 4, stream);

    cvt_all<<<2756, 256, 0, stream>>>(x, xb, W1a, W1b, W2a, W2b, wt);
    count_deg<<<(NE + 255) / 256, 256, 0, stream>>>(ei, degcnt);
    scan_deg<<<1, 256, 0, stream>>>(degcnt, off);
    fill_csr<<<(NE + 255) / 256, 256, 0, stream>>>(ei, off, fillc, ssrc);

    // layer 1
    agg_bf16<<<5000, 256, 0, stream>>>(xb, bufA, off, ssrc);
    gemm_mfma<<<157, 256, 0, stream>>>(bufA, wt + 0 * 16384, b1a, bufB, 1);
    gemm_mfma<<<157, 256, 0, stream>>>(bufB, wt + 1 * 16384, b1b, bufA, 1);  // + outer relu
    // layer 2
    agg_bf16<<<5000, 256, 0, stream>>>(bufA, bufB, off, ssrc);
    gemm_mfma<<<157, 256, 0, stream>>>(bufB, wt + 2 * 16384, b2a, bufA, 1);
    gemm_mfma<<<157, 256, 0, stream>>>(bufA, wt + 3 * 16384, b2b, bufB, 1);  // + outer relu
    // pool + fc
    pool_partial<<<500, 256, 0, stream>>>(bufB, batch, gsum);
    pool_final<<<NG, 128, 0, stream>>>(gsum, batch, fcw, fcb, out);
}

// Round 3
// 262.013 us; speedup vs baseline: 2.1638x; 1.2124x over previous
//
#include <hip/hip_runtime.h>

#define NN 20000
#define NE 640000
#define CH 128
#define NG 64
#define NSLICE (NN / 8)   // 2500 nodes per XCD slice

typedef unsigned short u16;
typedef __attribute__((ext_vector_type(8))) short short8;   // 8 bf16 (4 VGPRs)
typedef __attribute__((ext_vector_type(4))) float floatx4;  // 4 fp32 acc

__device__ __forceinline__ float b2f(u16 u) {
    union { float f; unsigned int i; } v; v.i = ((unsigned int)u) << 16; return v.f;
}
__device__ __forceinline__ u16 f2b(float f) {
    unsigned int u = __float_as_uint(f);
    u += 0x7fff + ((u >> 16) & 1);          // RNE
    return (u16)(u >> 16);
}

// ---- convert x -> bf16; weights -> bf16 in MFMA B-frag order --------------
// frag order: flat = (((ct*4+kc)*4+quad)*16+l16)*8+j ; value = W[k][n],
// n = ct*16+l16 (output col), k = kc*32+quad*8+j
__global__ __launch_bounds__(256) void cvt_all(const float* __restrict__ x, u16* __restrict__ xb,
                                               const float* __restrict__ W1a, const float* __restrict__ W1b,
                                               const float* __restrict__ W2a, const float* __restrict__ W2b,
                                               u16* __restrict__ wt) {
    int b = blockIdx.x;
    if (b < 2500) {                                   // x: 2.56M elems, 4/thread
        int idx = (b * 256 + threadIdx.x) * 4;
        float4 v = *(const float4*)(x + idx);
        ushort4 o = make_ushort4(f2b(v.x), f2b(v.y), f2b(v.z), f2b(v.w));
        *(ushort4*)(xb + idx) = o;
    } else {                                          // weights: 4 x 16384 elems
        int wi = b - 2500;                            // 0..255
        int m = wi >> 6;
        int r = (wi & 63) * 256 + threadIdx.x;        // 0..16383
        int j = r & 7, l16 = (r >> 3) & 15, quad = (r >> 7) & 3;
        int kc = (r >> 9) & 3, ct = (r >> 11) & 7;
        int n = ct * 16 + l16, k = kc * 32 + quad * 8 + j;
        const float* W = (m == 0) ? W1a : (m == 1) ? W1b : (m == 2) ? W2a : W2b;
        wt[m * 16384 + r] = f2b(W[k * 128 + n]);
    }
}

// ---- CSR pass A: histogram + rank in one atomic pass ----------------------
__global__ __launch_bounds__(256) void pass_rank(const int* __restrict__ ei,
                                                 int* __restrict__ cnt, int* __restrict__ rank) {
    int e = blockIdx.x * 256 + threadIdx.x;
    if (e < NE) rank[e] = atomicAdd(&cnt[ei[NE + e]], 1);
}

// ---- scan cnt -> off ------------------------------------------------------
__global__ void scan_deg(const int* __restrict__ cnt, int* __restrict__ off) {
    __shared__ int psum[256];
    __shared__ int ex[256];
    int t = threadIdx.x;
    const int chunk = (NN + 255) / 256;
    int lo = t * chunk;
    int hi = lo + chunk; if (hi > NN) hi = NN; if (lo > NN) lo = NN;
    int s = 0;
    for (int i = lo; i < hi; ++i) s += cnt[i];
    psum[t] = s;
    __syncthreads();
    if (t == 0) {
        int run = 0;
        for (int i = 0; i < 256; ++i) { ex[i] = run; run += psum[i]; }
    }
    __syncthreads();
    int run = ex[t];
    for (int i = lo; i < hi; ++i) { off[i] = run; run += cnt[i]; }
    if (t == 0) off[NN] = NE;
}

// ---- CSR pass C: atomic-free, XCD-sliced scatter --------------------------
// slice = blockIdx%8 (XCD heuristic): each XCD scatters only into its 320KB
// ssrc slice -> stays L2-resident. Correct regardless of actual mapping.
__global__ __launch_bounds__(256) void fill_sliced(const int* __restrict__ ei,
                                                   const int* __restrict__ off,
                                                   const int* __restrict__ rank,
                                                   int* __restrict__ ssrc) {
    int slice = blockIdx.x & 7;
    int chunk = blockIdx.x >> 3;                      // 0..127
    int lo = slice * NSLICE, hi = lo + NSLICE;
    int e0 = chunk * 5000, e1 = e0 + 5000;            // 128*5000 = NE
    for (int e = e0 + threadIdx.x; e < e1; e += 256) {
        int dst = ei[NE + e];
        if (dst >= lo && dst < hi)
            ssrc[off[dst] + rank[e]] = ei[e];
    }
}

// ---- aggregate (bf16): out[n] = in[n] + sum_{e:dst==n} in[src[e]] ---------
// one wave/node: 4 edge-slots x 16 ch-groups (16B loads); unroll 4 -> 4 gathers in flight
__global__ __launch_bounds__(256) void agg_bf16(const u16* __restrict__ in, u16* __restrict__ out,
                                                const int* __restrict__ off, const int* __restrict__ ssrc) {
    int n = (blockIdx.x * 256 + threadIdx.x) >> 6;
    int lane = threadIdx.x & 63;
    int slot = lane >> 4, cg = lane & 15;
    int boff = cg * 8;
    float acc[8];
    if (slot == 0) {
        short8 v = *(const short8*)(in + (size_t)n * CH + boff);
        #pragma unroll
        for (int j = 0; j < 8; ++j) acc[j] = b2f((u16)v[j]);
    } else {
        #pragma unroll
        for (int j = 0; j < 8; ++j) acc[j] = 0.f;
    }
    int b = off[n], e = off[n + 1];
    int i = b + slot;
    for (; i + 12 < e; i += 16) {
        int s0 = ssrc[i], s1 = ssrc[i + 4], s2 = ssrc[i + 8], s3 = ssrc[i + 12];
        short8 v0 = *(const short8*)(in + (size_t)s0 * CH + boff);
        short8 v1 = *(const short8*)(in + (size_t)s1 * CH + boff);
        short8 v2 = *(const short8*)(in + (size_t)s2 * CH + boff);
        short8 v3 = *(const short8*)(in + (size_t)s3 * CH + boff);
        #pragma unroll
        for (int j = 0; j < 8; ++j)
            acc[j] += (b2f((u16)v0[j]) + b2f((u16)v1[j])) + (b2f((u16)v2[j]) + b2f((u16)v3[j]));
    }
    for (; i < e; i += 4) {
        int s0 = ssrc[i];
        short8 v0 = *(const short8*)(in + (size_t)s0 * CH + boff);
        #pragma unroll
        for (int j = 0; j < 8; ++j) acc[j] += b2f((u16)v0[j]);
    }
    #pragma unroll
    for (int j = 0; j < 8; ++j) {
        acc[j] += __shfl_xor(acc[j], 16);
        acc[j] += __shfl_xor(acc[j], 32);
    }
    if (slot == 0) {
        short8 o;
        #pragma unroll
        for (int j = 0; j < 8; ++j) o[j] = (short)f2b(acc[j]);
        *(short8*)(out + (size_t)n * CH + boff) = o;
    }
}

// ---- fused MLP: out = relu( relu(A@Wa+ba) @ Wb + bb ) ---------------------
// 256 thr = 4 waves, 128 rows/block, wave = 32 rows x 128 cols.
// H round-trips through a wave-private LDS region -> NO barriers needed.
// W frags load straight from global (pre-swizzled, coalesced, L2-hot).
__global__ __launch_bounds__(256) void mlp_fused(const u16* __restrict__ A,
                                                 const u16* __restrict__ wtA, const u16* __restrict__ wtB,
                                                 const float* __restrict__ biasA, const float* __restrict__ biasB,
                                                 u16* __restrict__ out) {
    __shared__ u16 H[128 * 136];                      // +8 pad: 16B-aligned rows, <=2-way banks
    int t = threadIdx.x, wave = t >> 6, lane = t & 63;
    int quad = lane >> 4, l16 = lane & 15;
    int row0 = blockIdx.x * 128 + wave * 32;

    short8 af[2][4];                                   // A[m=l16][k=quad*8+j]
    #pragma unroll
    for (int rt = 0; rt < 2; ++rt) {
        int r = row0 + rt * 16 + l16; if (r >= NN) r = NN - 1;
        #pragma unroll
        for (int kc = 0; kc < 4; ++kc)
            af[rt][kc] = *(const short8*)(A + (size_t)r * CH + kc * 32 + quad * 8);
    }

    // GEMM1, per-ct epilogue into LDS (keeps acc1 live range = 8 regs)
    #pragma unroll
    for (int ct = 0; ct < 8; ++ct) {
        floatx4 a0 = (floatx4)(0.f), a1 = (floatx4)(0.f);
        #pragma unroll
        for (int kc = 0; kc < 4; ++kc) {
            short8 bf = *(const short8*)(wtA + (((ct * 4 + kc) * 4 + quad) * 16 + l16) * 8);
            a0 = __builtin_amdgcn_mfma_f32_16x16x32_bf16(af[0][kc], bf, a0, 0, 0, 0);
            a1 = __builtin_amdgcn_mfma_f32_16x16x32_bf16(af[1][kc], bf, a1, 0, 0, 0);
        }
        float bv = biasA[ct * 16 + l16];
        #pragma unroll
        for (int r = 0; r < 4; ++r) {
            int lr0 = wave * 32 + 0 * 16 + quad * 4 + r;   // C/D: row=quad*4+r, col=l16
            int lr1 = wave * 32 + 1 * 16 + quad * 4 + r;
            H[lr0 * 136 + ct * 16 + l16] = f2b(fmaxf(a0[r] + bv, 0.f));
            H[lr1 * 136 + ct * 16 + l16] = f2b(fmaxf(a1[r] + bv, 0.f));
        }
    }

    // GEMM2: A-frags from wave-private H rows (written by this wave only)
    short8 af2[2][4];
    #pragma unroll
    for (int rt = 0; rt < 2; ++rt)
        #pragma unroll
        for (int kc = 0; kc < 4; ++kc)
            af2[rt][kc] = *(const short8*)&H[(wave * 32 + rt * 16 + l16) * 136 + kc * 32 + quad * 8];

    #pragma unroll
    for (int ct = 0; ct < 8; ++ct) {
        floatx4 a0 = (floatx4)(0.f), a1 = (floatx4)(0.f);
        #pragma unroll
        for (int kc = 0; kc < 4; ++kc) {
            short8 bf = *(const short8*)(wtB + (((ct * 4 + kc) * 4 + quad) * 16 + l16) * 8);
            a0 = __builtin_amdgcn_mfma_f32_16x16x32_bf16(af2[0][kc], bf, a0, 0, 0, 0);
            a1 = __builtin_amdgcn_mfma_f32_16x16x32_bf16(af2[1][kc], bf, a1, 0, 0, 0);
        }
        int col = ct * 16 + l16;
        float bv = biasB[col];
        #pragma unroll
        for (int rt = 0; rt < 2; ++rt) {
            floatx4 av = rt ? a1 : a0;
            #pragma unroll
            for (int r = 0; r < 4; ++r) {
                int row = row0 + rt * 16 + quad * 4 + r;
                if (row < NN)
                    out[(size_t)row * CH + col] = f2b(fmaxf(av[r] + bv, 0.f));
            }
        }
    }
}

// ---- pool: run-length partial sums -> atomics, then per-graph fc ----------
__global__ __launch_bounds__(256) void pool_partial(const u16* __restrict__ h, const int* __restrict__ batch,
                                                    float* __restrict__ gsum) {
    int n0 = blockIdx.x * 40;
    int n1 = n0 + 40; if (n1 > NN) n1 = NN;
    int half = threadIdx.x >> 7, c = threadIdx.x & 127;
    float run = 0.f; int curg = -1;
    for (int n = n0 + half; n < n1; n += 2) {
        int g = batch[n];
        if (g != curg) {
            if (curg >= 0) atomicAdd(&gsum[curg * CH + c], run);
            run = 0.f; curg = g;
        }
        run += b2f(h[(size_t)n * CH + c]);
    }
    if (curg >= 0) atomicAdd(&gsum[curg * CH + c], run);
}

__global__ __launch_bounds__(128) void pool_final(const float* __restrict__ gsum, const int* __restrict__ batch,
                                                  const float* __restrict__ fcw, const float* __restrict__ fcb,
                                                  float* __restrict__ outp) {
    int g = blockIdx.x, t = threadIdx.x;
    __shared__ int se[2];
    if (t < 2) {
        int target = g + t, lo = 0, hi = NN;
        while (lo < hi) { int mid = (lo + hi) >> 1; if (batch[mid] < target) lo = mid + 1; else hi = mid; }
        se[t] = lo;
    }
    __syncthreads();
    int cnt = se[1] - se[0]; if (cnt < 1) cnt = 1;
    float v = gsum[g * CH + t] * fcw[t] / (float)cnt;
    __shared__ float red[128];
    red[t] = v; __syncthreads();
    for (int s = 64; s > 0; s >>= 1) { if (t < s) red[t] += red[t + s]; __syncthreads(); }
    if (t == 0) outp[g] = red[0] + fcb[0];
}

extern "C" void kernel_launch(void* const* d_in, const int* in_sizes, int n_in,
                              void* d_out, int out_size, void* d_ws, size_t ws_size,
                              hipStream_t stream) {
    const float* x   = (const float*)d_in[0];
    const int*   ei  = (const int*)d_in[1];
    const int* batch = (const int*)d_in[2];
    const float* W1a = (const float*)d_in[3];
    const float* b1a = (const float*)d_in[4];
    const float* W1b = (const float*)d_in[5];
    const float* b1b = (const float*)d_in[6];
    const float* W2a = (const float*)d_in[7];
    const float* b2a = (const float*)d_in[8];
    const float* W2b = (const float*)d_in[9];
    const float* b2b = (const float*)d_in[10];
    const float* fcw = (const float*)d_in[11];
    const float* fcb = (const float*)d_in[12];
    float* out = (float*)d_out;

    char* w = (char*)d_ws;
    u16* xb   = (u16*)w; w += (size_t)NN * CH * 2;
    u16* bufA = (u16*)w; w += (size_t)NN * CH * 2;
    u16* bufB = (u16*)w; w += (size_t)NN * CH * 2;
    u16* wt   = (u16*)w; w += (size_t)4 * 16384 * 2;
    int* cnt  = (int*)w; w += (size_t)NN * 4;        // cnt+gsum contiguous for one memset
    float* gsum = (float*)w; w += (size_t)NG * CH * 4;
    int* off  = (int*)w; w += (size_t)(NN + 1) * 4;
    int* rank = (int*)w; w += (size_t)NE * 4;
    int* ssrc = (int*)w; w += (size_t)NE * 4;

    hipMemsetAsync(cnt, 0, (size_t)(NN + NG * CH) * 4, stream);

    cvt_all<<<2756, 256, 0, stream>>>(x, xb, W1a, W1b, W2a, W2b, wt);
    pass_rank<<<(NE + 255) / 256, 256, 0, stream>>>(ei, cnt, rank);
    scan_deg<<<1, 256, 0, stream>>>(cnt, off);
    fill_sliced<<<1024, 256, 0, stream>>>(ei, off, rank, ssrc);

    // layer 1
    agg_bf16<<<5000, 256, 0, stream>>>(xb, bufA, off, ssrc);
    mlp_fused<<<157, 256, 0, stream>>>(bufA, wt + 0 * 16384, wt + 1 * 16384, b1a, b1b, bufB);
    // layer 2
    agg_bf16<<<5000, 256, 0, stream>>>(bufB, bufA, off, ssrc);
    mlp_fused<<<157, 256, 0, stream>>>(bufA, wt + 2 * 16384, wt + 3 * 16384, b2a, b2b, bufB);
    // pool + fc
    pool_partial<<<500, 256, 0, stream>>>(bufB, batch, gsum);
    pool_final<<<NG, 128, 0, stream>>>(gsum, batch, fcw, fcb, out);
}